// Round 2
// baseline (1802.976 us; speedup 1.0000x reference)
//
#include <hip/hip_runtime.h>

#define BATCH 32
#define DIM   3072
#define NTRAIN 100000
#define NBLK  256
#define JPB   391        /* ceil(100000/256) */
#define JT    16         /* j per subtile */
#define KC    512        /* k per chunk */
#define NCHUNK 6         /* DIM/KC */
#define WAVES 8
#define DPW   384        /* DIM/WAVES */
#define NTILE 12         /* DPW/32 */

/* LDS layout (bytes) */
#define TH_B   0u        /* [16][3072] bf16 swizzled, persists per subtile: 98304 B */
#define TL_B   98304u    /* 2 x [16][512] bf16 swizzled (double buffer):   32768 B */
#define ARED_B 98304u    /* alias TL0: [8][32][16] f32: 16384 B */
#define TSQ_B  114688u   /* alias TL1: [16] f32 */
#define LG_B   114752u   /* [32][17] f32: 2176 B */
#define CORR_B 116928u   /* [32] f32 */

typedef __bf16 bf16x8 __attribute__((ext_vector_type(8)));
typedef float  f32x4  __attribute__((ext_vector_type(4)));
typedef float  f32x16 __attribute__((ext_vector_type(16)));
typedef unsigned short u16;
typedef unsigned int   u32;

union F8 { u16 us[8]; u32 ui[4]; uint4 u4; bf16x8 bf; };

__device__ __forceinline__ u16   bft(float f){ return (u16)(__float_as_uint(f) >> 16); }
__device__ __forceinline__ float bfh(float f){ return __uint_as_float(__float_as_uint(f) & 0xFFFF0000u); }

/* swizzled byte offset inside a [16][3072] bf16 region (row stride 6144 B) */
__device__ __forceinline__ u32 offTH(u32 row, u32 kb){
    return row*6144u + (kb ^ ((row & 15u) << 4) ^ (((kb >> 6) & 3u) << 4));
}
/* swizzled byte offset inside a [16][512] bf16 region (row stride 1024 B) */
__device__ __forceinline__ u32 offTL(u32 row, u32 kb){
    return row*1024u + (kb ^ ((row & 15u) << 4) ^ (((kb >> 6) & 3u) << 4));
}

// ---------------- K0: split x into bf16 hi/lo ----------------
__global__ __launch_bounds__(256) void k0_split_x(
        const float* __restrict__ x, u16* __restrict__ xh, u16* __restrict__ xl) {
    int i = blockIdx.x * 256 + threadIdx.x;
    if (i >= BATCH * DIM) return;
    float f  = x[i];
    xh[i] = bft(f);
    xl[i] = bft(f - bfh(f));
}

// ---------------- fused: logits + online softmax + PV, one train pass ----------------
__global__ __launch_bounds__(512, 2) void fused_kernel(
        const float* __restrict__ train,
        const u16* __restrict__ xh, const u16* __restrict__ xl,
        const float* __restrict__ alphas, const int* __restrict__ tptr,
        float* __restrict__ partial,   // [NBLK][32][3072]
        float* __restrict__ m_arr,     // [NBLK][32]
        float* __restrict__ l_arr) {   // [NBLK][32]
    __shared__ __align__(16) char smem[131072];

    const int tid  = threadIdx.x;
    const int lane = tid & 63;
    const int w    = tid >> 6;        // wave 0..7
    const int l15  = lane & 15;
    const int q4   = lane >> 4;       // k-group for 16x16x32
    const int l31  = lane & 31;
    const int g32  = lane >> 5;       // k-group for 32x32x16
    const int bid  = blockIdx.x;

    const float ab = alphas[tptr[0]];
    const float s  = sqrtf(ab);
    const float om = 1.0f - ab;
    const float c1 = s / om;
    const float c2 = ab / (2.0f * om);

    const int jstart = bid * JPB;
    const int jlim   = min(jstart + JPB, NTRAIN);
    const int nsub   = (jlim - jstart + JT - 1) / JT;

    // staging mapping: 512 threads cover [16 rows][512 k] f32 per chunk
    const int srow = tid >> 5;   // 0..15
    const int sc   = tid & 31;   // 0..31

    f32x16 acc[NTILE];
#pragma unroll
    for (int t0 = 0; t0 < NTILE; ++t0)
#pragma unroll
        for (int r = 0; r < 16; ++r) acc[t0][r] = 0.0f;

    float m_run = -1e30f, l_run = 0.0f;

    for (int st = 0; st < nsub; ++st) {
        const int jbase = jstart + st * JT;
        __syncthreads();   // protect th region from previous phase C readers

        float tsqp = 0.0f;
        const int jg = min(jbase + srow, jlim - 1);
        const float* rbase = train + (size_t)jg * DIM + sc * 4;

        // convert + swizzled-write one float4 group (16 B) of chunk c, group i
        auto cvw = [&](float4 v, int c, int i) {
            u32 kbTH = (u32)(c * 1024 + i * 256 + sc * 8);
            u32 kbTL = (u32)(i * 256 + sc * 8);
            u32 h0 = (__float_as_uint(v.x) >> 16) | (__float_as_uint(v.y) & 0xFFFF0000u);
            u32 h1 = (__float_as_uint(v.z) >> 16) | (__float_as_uint(v.w) & 0xFFFF0000u);
            float lx = v.x - bfh(v.x), ly = v.y - bfh(v.y);
            float lz = v.z - bfh(v.z), lw = v.w - bfh(v.w);
            u32 e0 = (__float_as_uint(lx) >> 16) | (__float_as_uint(ly) & 0xFFFF0000u);
            u32 e1 = (__float_as_uint(lz) >> 16) | (__float_as_uint(lw) & 0xFFFF0000u);
            *(uint2*)(smem + TH_B + offTH((u32)srow, kbTH)) = make_uint2(h0, h1);
            *(uint2*)(smem + TL_B + (u32)(c & 1) * 16384u + offTL((u32)srow, kbTL)) = make_uint2(e0, e1);
            tsqp = fmaf(v.x, v.x, tsqp); tsqp = fmaf(v.y, v.y, tsqp);
            tsqp = fmaf(v.z, v.z, tsqp); tsqp = fmaf(v.w, v.w, tsqp);
        };

        // ---- prologue: stage chunk 0 ----
        {
            const float* rp = rbase;  // chunk 0
            float4 P0 = *(const float4*)(rp +   0);
            float4 P1 = *(const float4*)(rp + 128);
            float4 P2 = *(const float4*)(rp + 256);
            float4 P3 = *(const float4*)(rp + 384);
            cvw(P0, 0, 0); cvw(P1, 0, 1); cvw(P2, 0, 2); cvw(P3, 0, 3);
        }
        __syncthreads();

        f32x4 acc0 = {0.f, 0.f, 0.f, 0.f};
        f32x4 acc1 = {0.f, 0.f, 0.f, 0.f};

        for (int c = 0; c < NCHUNK; ++c) {
            float4 P0, P1, P2, P3;
            if (c < NCHUNK - 1) {   // issue next chunk's loads early (fly under compute)
                const float* rp = rbase + (c + 1) * KC;
                P0 = *(const float4*)(rp +   0);
                P1 = *(const float4*)(rp + 128);
                P2 = *(const float4*)(rp + 256);
                P3 = *(const float4*)(rp + 384);
            }
            // ---- phase A compute on chunk c: this wave's 64-k slice ----
#pragma unroll
            for (int ks = 0; ks < 2; ++ks) {
                const u32 kg = (u32)(c * KC + w * 64 + ks * 32 + q4 * 8);
                F8 ah0, ah1, al0, al1, bh, bl;
                ah0.u4 = *(const uint4*)(xh + (size_t)l15 * DIM + kg);
                ah1.u4 = *(const uint4*)(xh + (size_t)(l15 + 16) * DIM + kg);
                al0.u4 = *(const uint4*)(xl + (size_t)l15 * DIM + kg);
                al1.u4 = *(const uint4*)(xl + (size_t)(l15 + 16) * DIM + kg);
                bh.u4 = *(const uint4*)(smem + TH_B + offTH((u32)l15, kg * 2));
                bl.u4 = *(const uint4*)(smem + TL_B + (u32)(c & 1) * 16384u
                                        + offTL((u32)l15, (kg - c * KC) * 2));
                acc0 = __builtin_amdgcn_mfma_f32_16x16x32_bf16(ah0.bf, bh.bf, acc0, 0, 0, 0);
                acc0 = __builtin_amdgcn_mfma_f32_16x16x32_bf16(al0.bf, bh.bf, acc0, 0, 0, 0);
                acc0 = __builtin_amdgcn_mfma_f32_16x16x32_bf16(ah0.bf, bl.bf, acc0, 0, 0, 0);
                acc1 = __builtin_amdgcn_mfma_f32_16x16x32_bf16(ah1.bf, bh.bf, acc1, 0, 0, 0);
                acc1 = __builtin_amdgcn_mfma_f32_16x16x32_bf16(al1.bf, bh.bf, acc1, 0, 0, 0);
                acc1 = __builtin_amdgcn_mfma_f32_16x16x32_bf16(ah1.bf, bl.bf, acc1, 0, 0, 0);
            }
            if (c < NCHUNK - 1) {
                cvw(P0, c + 1, 0); cvw(P1, c + 1, 1); cvw(P2, c + 1, 2); cvw(P3, c + 1, 3);
            }
            __syncthreads();
        }

        // ---- cross-wave reduce of logits partials + tsq ----
#pragma unroll
        for (int r = 0; r < 4; ++r) {
            int b0 = q4 * 4 + r;
            *(float*)(smem + ARED_B + ((u32)(w * 512 + b0 * 16 + l15)) * 4u)        = acc0[r];
            *(float*)(smem + ARED_B + ((u32)(w * 512 + (b0 + 16) * 16 + l15)) * 4u) = acc1[r];
        }
        {
            float tq = tsqp;
            tq += __shfl_xor(tq, 1);  tq += __shfl_xor(tq, 2);
            tq += __shfl_xor(tq, 4);  tq += __shfl_xor(tq, 8);
            tq += __shfl_xor(tq, 16);
            if (sc == 0) *(float*)(smem + TSQ_B + (u32)srow * 4u) = tq;
        }
        __syncthreads();
        {
            int b = tid >> 4, j = tid & 15;
            float v = 0.0f;
#pragma unroll
            for (int wv_ = 0; wv_ < 8; ++wv_)
                v += *(const float*)(smem + ARED_B + ((u32)(wv_ * 512 + b * 16 + j)) * 4u);
            float lg = c1 * v - c2 * (*(const float*)(smem + TSQ_B + (u32)j * 4u));
            if (jbase + j >= jlim) lg = -3e38f;
            *(float*)(smem + LG_B + ((u32)(b * 17 + j)) * 4u) = lg;
        }
        __syncthreads();

        // ---- phase B: online softmax (each wave redundantly; lane owns b=l31) ----
        float wv[16];
        float pmax = -3e38f;
#pragma unroll
        for (int j = 0; j < 16; ++j) {
            wv[j] = *(const float*)(smem + LG_B + ((u32)(l31 * 17 + j)) * 4u);
            pmax = fmaxf(pmax, wv[j]);
        }
        const float nm   = fmaxf(m_run, pmax);
        const float corr = __expf(m_run - nm);
        float psum = 0.0f;
#pragma unroll
        for (int j = 0; j < 16; ++j) { wv[j] = __expf(wv[j] - nm); psum += wv[j]; }
        l_run = l_run * corr + psum;
        m_run = nm;
        *(float*)(smem + CORR_B + (u32)l31 * 4u) = corr;  // identical dup writes: benign

        float cr[16];
#pragma unroll
        for (int r = 0; r < 16; ++r) {
            int brow = (r & 3) + 8 * (r >> 2) + 4 * g32;
            cr[r] = *(const float*)(smem + CORR_B + (u32)brow * 4u);
        }
#pragma unroll
        for (int t0 = 0; t0 < NTILE; ++t0)
#pragma unroll
            for (int r = 0; r < 16; ++r) acc[t0][r] *= cr[r];

        F8 af;
#pragma unroll
        for (int e = 0; e < 8; ++e) {
            float we = g32 ? wv[8 + e] : wv[e];
            af.us[e] = bft(we);
        }

        // ---- phase C: PV from persistent th region (K = 16 j's) ----
#pragma unroll
        for (int t0 = 0; t0 < NTILE; ++t0) {
            const u32 d = (u32)(w * DPW + t0 * 32 + l31);
            F8 bfr;
#pragma unroll
            for (int e = 0; e < 8; ++e) {
                u32 j = (u32)(8 * g32 + e);
                bfr.us[e] = *(const u16*)(smem + TH_B + offTH(j, d * 2));
            }
            acc[t0] = __builtin_amdgcn_mfma_f32_32x32x16_bf16(af.bf, bfr.bf, acc[t0], 0, 0, 0);
        }
    }

    // ---- epilogue: write per-block partials + (m, l) ----
#pragma unroll
    for (int t0 = 0; t0 < NTILE; ++t0) {
        int d = w * DPW + t0 * 32 + l31;
#pragma unroll
        for (int r = 0; r < 16; ++r) {
            int brow = (r & 3) + 8 * (r >> 2) + 4 * g32;
            partial[((size_t)bid * BATCH + brow) * DIM + d] = acc[t0][r];
        }
    }
    if (tid < 32) {
        m_arr[bid * 32 + tid] = m_run;
        l_arr[bid * 32 + tid] = l_run;
    }
}

// ---------------- final: log-sum-exp merge of per-block partials ----------------
__global__ __launch_bounds__(256) void final_kernel(
        const float* __restrict__ x, const float* __restrict__ partial,
        const float* __restrict__ m_arr, const float* __restrict__ l_arr,
        const float* __restrict__ alphas, const int* __restrict__ tptr,
        float* __restrict__ out) {
    int i = blockIdx.x * 256 + threadIdx.x;
    if (i >= BATCH * DIM) return;
    int b = i / DIM;
    float ab = alphas[tptr[0]];
    float s  = sqrtf(ab);
    float om = 1.0f - ab;
    float inv = 1.0f / sqrtf(om);
    float M = -3e38f;
#pragma unroll 4
    for (int k = 0; k < NBLK; ++k) M = fmaxf(M, m_arr[k * 32 + b]);
    float L = 0.0f, wsum = 0.0f;
#pragma unroll 4
    for (int k = 0; k < NBLK; ++k) {
        float e = __expf(m_arr[k * 32 + b] - M);
        L    += l_arr[k * 32 + b] * e;
        wsum += partial[(size_t)k * (BATCH * DIM) + i] * e;
    }
    out[i] = inv * x[i] - s * inv * (wsum / L);
}

extern "C" void kernel_launch(void* const* d_in, const int* in_sizes, int n_in,
                              void* d_out, int out_size, void* d_ws, size_t ws_size,
                              hipStream_t stream) {
    const float* x      = (const float*)d_in[0];
    const float* train  = (const float*)d_in[1];
    const float* alphas = (const float*)d_in[2];
    const int*   tptr   = (const int*)d_in[3];
    float* out = (float*)d_out;

    char* ws = (char*)d_ws;
    float* partial = (float*)ws;                                   // 100,663,296 B
    float* m_arr   = (float*)(ws + 100663296);                     // 32,768 B
    float* l_arr   = (float*)(ws + 100663296 + 32768);             // 32,768 B
    u16*   xh      = (u16*)(ws + 100663296 + 65536);               // 196,608 B
    u16*   xl      = (u16*)(ws + 100663296 + 65536 + 196608);      // 196,608 B

    k0_split_x<<<(BATCH * DIM + 255) / 256, 256, 0, stream>>>(x, xh, xl);
    fused_kernel<<<NBLK, 512, 0, stream>>>(train, xh, xl, alphas, tptr,
                                           partial, m_arr, l_arr);
    final_kernel<<<(BATCH * DIM + 255) / 256, 256, 0, stream>>>(
        x, partial, m_arr, l_arr, alphas, tptr, out);
}